// Round 10
// baseline (134.680 us; speedup 1.0000x reference)
//
#include <hip/hip_runtime.h>
#include <hip/hip_fp16.h>
#include <math.h>

#define B 4
#define T 4096
#define DEMB 512
#define DH 64
#define NSPLIT 16
#define NPTILE 16            // 256-row q-tiles per batch
#define LOG2E 1.44269504088896340736f

typedef _Float16 f16;
typedef __attribute__((ext_vector_type(4))) _Float16 f16x4;
typedef __attribute__((ext_vector_type(8))) _Float16 f16x8;
typedef __attribute__((ext_vector_type(4))) float f32x4;

// ---------------------------------------------------------------------------
// W prepass: concat Wq|Wk|Wv -> [192][512] fp16.
// ---------------------------------------------------------------------------
__global__ __launch_bounds__(256) void convert_w(
    const float* __restrict__ Wq, const float* __restrict__ Wk,
    const float* __restrict__ Wv, f16* __restrict__ Wf)
{
    const int idx = blockIdx.x * 256 + threadIdx.x;     // covers 192*512
    const int row = idx >> 9;
    const int k   = idx & 511;
    const float* W = row < 64 ? Wq : (row < 128 ? Wk : Wv);
    Wf[idx] = (f16)W[(row & 63) * DEMB + k];
}

// ---------------------------------------------------------------------------
// QKV projection, fp16 MFMA GEMM: [16384x512] x [512x192].
// 512 blocks x 8 waves; block = 32 x-rows, all 192 cols; k-chunks of 128.
// LDS 61 KB -> 2 blocks/CU: stage/compute phases of the two resident blocks
// interleave, hiding global-load latency (vs R9's 1 block/CU serialization).
// Wave = (rg = wv>>2: 16-row group) x (nh = wv&3: 3 of 12 n-tiles).
// Q is written PRE-SCALED by log2(e) so attention softmax can use exp2.
// ---------------------------------------------------------------------------
__global__ __launch_bounds__(512) void proj_mfma(
    const float* __restrict__ x, const f16* __restrict__ Wfg,
    const float* __restrict__ bq, const float* __restrict__ bk,
    const float* __restrict__ bv,
    f16* __restrict__ Qf, f16* __restrict__ Kf, f16* __restrict__ Vt)
{
    __shared__ f16 xs[32][136];           // 8704 B (272 B rows)
    __shared__ f16 Ws[192][136];          // 52224 B -> 60928 B total

    const int tid  = threadIdx.x;
    const int wv   = tid >> 6;
    const int lane = tid & 63;
    const int i16  = lane & 15;
    const int quad = lane >> 4;
    const int rg   = wv >> 2;             // 16-row group 0..1
    const int nh   = wv & 3;              // n-quarter (3 tiles)
    const size_t r0 = (size_t)blockIdx.x * 32;

    f32x4 acc[3];
    const f32x4 zero = {0.f, 0.f, 0.f, 0.f};
#pragma unroll
    for (int n = 0; n < 3; ++n) acc[n] = zero;

    for (int cc = 0; cc < DEMB; cc += 128) {
        __syncthreads();
        // stage x: 32 rows x 128 cols fp32 -> fp16 (512 groups of 8; 1/thread)
        {
            const int row = tid >> 4, g = tid & 15;
            const float4 a = *(const float4*)(x + (r0 + row) * DEMB + cc + g * 8);
            const float4 b = *(const float4*)(x + (r0 + row) * DEMB + cc + g * 8 + 4);
            f16x8 h = {(f16)a.x, (f16)a.y, (f16)a.z, (f16)a.w,
                       (f16)b.x, (f16)b.y, (f16)b.z, (f16)b.w};
            *(f16x8*)&xs[row][g * 8] = h;
        }
        // stage W: 192 rows x 128 cols fp16 (3072 groups of 8; 6/thread)
#pragma unroll
        for (int u = 0; u < 6; ++u) {
            const int idx = tid + 512 * u;
            const int row = idx >> 4, g = idx & 15;
            *(f16x8*)&Ws[row][g * 8] =
                *(const f16x8*)(Wfg + (size_t)row * DEMB + cc + g * 8);
        }
        __syncthreads();

#pragma unroll
        for (int kk = 0; kk < 4; ++kk) {
            const f16x8 af = *(const f16x8*)&xs[rg * 16 + i16][kk * 32 + quad * 8];
#pragma unroll
            for (int n = 0; n < 3; ++n) {
                const f16x8 bf = *(const f16x8*)&Ws[(nh * 3 + n) * 16 + i16][kk * 32 + quad * 8];
                acc[n] = __builtin_amdgcn_mfma_f32_16x16x32_f16(af, bf, acc[n], 0, 0, 0);
            }
        }
    }

    const size_t bb = r0 / T;                  // uniform per block (32 | 4096)
    const size_t t0 = r0 - bb * T;
#pragma unroll
    for (int n = 0; n < 3; ++n) {
        const int col = (nh * 3 + n) * 16 + i16;    // 0..191
        const int m = col >> 6, h = col & 63;
        const float bias = (m == 0 ? bq : (m == 1 ? bk : bv))[h];
#pragma unroll
        for (int r = 0; r < 4; ++r) {
            const int row = rg * 16 + quad * 4 + r;
            const float v = acc[n][r] + bias;
            const size_t grow = r0 + row;
            if (m == 0)      Qf[grow * DH + h] = (f16)(v * LOG2E);  // log2-domain
            else if (m == 1) Kf[grow * DH + h] = (f16)v;
            else             Vt[(bb * DH + h) * T + t0 + row] = (f16)v;
        }
    }
}

// ---------------------------------------------------------------------------
// Attention pass 1 (TRANSPOSED layout; softmax in base 2 — Q pre-scaled).
//   St = K·Q^T  (C/D: col=lane&15 = q, row = k-local)  -> per-lane q-row
//   softmax stats: VALU + 2 shuffles; exp2f (native v_exp, no mul)
//   P^T packed f16x4 -> ds_write_b64; alpha applied to O^T with NO shuffle
//   O^T = V^T·P^T (A-frag = Vt rows from LDS, B-frag = P^T rows, b128)
// Grid (b, ptile, split) = 4 x 16 x 16 = 1024 blocks; block = 8 waves,
// each wave owns q-groups wv and wv+8 (2 x 16 rows) sharing K/V fragments.
// ---------------------------------------------------------------------------
__global__ __launch_bounds__(512, 4) void attn_partial(
    const f16* __restrict__ Qf, const f16* __restrict__ Kf,
    const f16* __restrict__ Vt,
    f16* __restrict__ Opart, float* __restrict__ mpart,
    float* __restrict__ lpart)
{
    __shared__ f16 Ks[64][72], Vs[64][72];      // 18432 B
    __shared__ f16 Pl[8][16][72];               // 18432 B -> 36 KB total

    const int tid  = threadIdx.x;
    const int wv   = tid >> 6;      // 0..7
    const int lane = tid & 63;
    const int i16  = lane & 15;
    const int quad = lane >> 4;

    const int s    = blockIdx.x & 15;
    const int p    = 15 - ((blockIdx.x >> 4) & 15);   // biggest tiles first
    const int bb   = blockIdx.x >> 8;
    const size_t base = (size_t)bb * T;
    const int row0 = p * 256;
    const int cmax = 4 * p + 3;
    const int rowg0 = row0 + wv * 16;
    const int rowg1 = row0 + (wv + 8) * 16;

    // Q B-frags (held in registers for the whole kernel)
    f16x8 qf00, qf01, qf10, qf11;
    {
        const f16* q0 = Qf + (base + rowg0 + i16) * DH;
        const f16* q1 = Qf + (base + rowg1 + i16) * DH;
        qf00 = *(const f16x8*)(q0 + quad * 8);
        qf01 = *(const f16x8*)(q0 + 32 + quad * 8);
        qf10 = *(const f16x8*)(q1 + quad * 8);
        qf11 = *(const f16x8*)(q1 + 32 + quad * 8);
    }

    f32x4 oacc[2][4];
    float mm[2] = {-INFINITY, -INFINITY}, ll[2] = {0.f, 0.f};
    const f32x4 zero = {0.f, 0.f, 0.f, 0.f};
#pragma unroll
    for (int j = 0; j < 2; ++j)
#pragma unroll
        for (int n = 0; n < 4; ++n) oacc[j][n] = zero;

    const int srow = tid >> 3, sg = tid & 7;

    for (int c = s; c <= cmax; c += NSPLIT) {
        const int kb = c << 6;
        __syncthreads();
        *(f16x8*)&Ks[srow][sg * 8] =
            *(const f16x8*)(Kf + (base + kb + srow) * DH + sg * 8);
        *(f16x8*)&Vs[srow][sg * 8] =
            *(const f16x8*)(Vt + ((size_t)bb * DH + srow) * T + kb + sg * 8);
        __syncthreads();

        const bool a0 = kb <= rowg0, a1 = kb <= rowg1;  // a0 => a1
        if (!a1) continue;                  // barriers at loop top stay uniform

        // ---- St = K·Q^T, shared K A-frags  (scores already in log2 units)
        f32x4 st[2][4];
#pragma unroll
        for (int kt = 0; kt < 4; ++kt) {
            const f16x8 kf0 = *(const f16x8*)&Ks[kt * 16 + i16][quad * 8];
            const f16x8 kf1 = *(const f16x8*)&Ks[kt * 16 + i16][32 + quad * 8];
            if (a0) {
                f32x4 a = __builtin_amdgcn_mfma_f32_16x16x32_f16(kf0, qf00, zero, 0, 0, 0);
                st[0][kt] = __builtin_amdgcn_mfma_f32_16x16x32_f16(kf1, qf01, a, 0, 0, 0);
            }
            {
                f32x4 a = __builtin_amdgcn_mfma_f32_16x16x32_f16(kf0, qf10, zero, 0, 0, 0);
                st[1][kt] = __builtin_amdgcn_mfma_f32_16x16x32_f16(kf1, qf11, a, 0, 0, 0);
            }
        }
        // ---- per-group softmax + P^T write + P^T read-back
        f16x8 pf[2][2];
#pragma unroll
        for (int j = 0; j < 2; ++j) {
            if (j == 0 && !a0) continue;
            const int rowg = j == 0 ? rowg0 : rowg1;
            if (kb + 63 > rowg) {           // diagonal chunk: causal mask
#pragma unroll
                for (int kt = 0; kt < 4; ++kt)
#pragma unroll
                    for (int r = 0; r < 4; ++r)
                        if (kb + kt * 16 + quad * 4 + r > rowg + i16)
                            st[j][kt][r] = -INFINITY;
            }
            float mx = -INFINITY;
#pragma unroll
            for (int kt = 0; kt < 4; ++kt)
#pragma unroll
                for (int r = 0; r < 4; ++r) mx = fmaxf(mx, st[j][kt][r]);
            mx = fmaxf(mx, __shfl_xor(mx, 16, 64));
            mx = fmaxf(mx, __shfl_xor(mx, 32, 64));
            const float mnew = fmaxf(mm[j], mx);        // finite: kb <= rowg
            const float alpha = exp2f(mm[j] - mnew);
            mm[j] = mnew;
            float sum = 0.f;
#pragma unroll
            for (int kt = 0; kt < 4; ++kt) {
                f16x4 pk;
#pragma unroll
                for (int r = 0; r < 4; ++r) {
                    const f16 pb = (f16)exp2f(st[j][kt][r] - mnew);
                    pk[r] = pb;
                    sum += (float)pb;       // l sums ROUNDED p (matches PV)
                }
                *(f16x4*)&Pl[wv][i16][kt * 16 + quad * 4] = pk;
            }
            sum += __shfl_xor(sum, 16, 64);
            sum += __shfl_xor(sum, 32, 64);
            ll[j] = ll[j] * alpha + sum;
#pragma unroll
            for (int n = 0; n < 4; ++n) oacc[j][n] *= alpha;   // col=q=i16: no shuffle
            pf[j][0] = *(const f16x8*)&Pl[wv][i16][quad * 8];
            pf[j][1] = *(const f16x8*)&Pl[wv][i16][32 + quad * 8];
        }
        // ---- O^T += V^T·P^T, shared V A-frags
#pragma unroll
        for (int mt = 0; mt < 4; ++mt) {
            const f16x8 vf0 = *(const f16x8*)&Vs[mt * 16 + i16][quad * 8];
            const f16x8 vf1 = *(const f16x8*)&Vs[mt * 16 + i16][32 + quad * 8];
            if (a0) {
                oacc[0][mt] = __builtin_amdgcn_mfma_f32_16x16x32_f16(vf0, pf[0][0], oacc[0][mt], 0, 0, 0);
                oacc[0][mt] = __builtin_amdgcn_mfma_f32_16x16x32_f16(vf1, pf[0][1], oacc[0][mt], 0, 0, 0);
            }
            oacc[1][mt] = __builtin_amdgcn_mfma_f32_16x16x32_f16(vf0, pf[1][0], oacc[1][mt], 0, 0, 0);
            oacc[1][mt] = __builtin_amdgcn_mfma_f32_16x16x32_f16(vf1, pf[1][1], oacc[1][mt], 0, 0, 0);
        }
    }

    // ---- epilogue: O^T regs -> Opart rows (lane i16 = q)
    f16* Ob = Opart + (size_t)blockIdx.x * (256 * 64);
#pragma unroll
    for (int j = 0; j < 2; ++j) {
        const int prow = (wv + 8 * j) * 16 + i16;       // tile-local q-row
#pragma unroll
        for (int mt = 0; mt < 4; ++mt) {
            f16x4 pk = {(f16)oacc[j][mt][0], (f16)oacc[j][mt][1],
                        (f16)oacc[j][mt][2], (f16)oacc[j][mt][3]};
            *(f16x4*)&Ob[prow * 64 + mt * 16 + quad * 4] = pk;
        }
        if (quad == 0) {
            mpart[(size_t)blockIdx.x * 256 + prow] = mm[j];
            lpart[(size_t)blockIdx.x * 256 + prow] = ll[j];
        }
    }
}

// ---------------------------------------------------------------------------
// Attention pass 2: combine split-partials (base-2 weights).
// Grid (b, p, sub) = 4 x 16 x 16 = 1024 blocks (4/CU); block = 16 rows.
// nact = min(16, 4p+4): splits beyond the causal frontier are skipped.
// ---------------------------------------------------------------------------
__global__ __launch_bounds__(256) void attn_combine(
    const f16* __restrict__ Opart, const float* __restrict__ mpart,
    const float* __restrict__ lpart, float* __restrict__ O)
{
    __shared__ float ws[16][NSPLIT];
    __shared__ float scl[16];

    const int tid = threadIdx.x;
    const int sub = blockIdx.x & 15;                 // 16-row slice
    const int p   = (blockIdx.x >> 4) & 15;
    const int bb  = blockIdx.x >> 8;
    const size_t pb0 = (size_t)bb * 256 + (15 - p) * 16;   // split block ids
    const int nact = min(NSPLIT, 4 * p + 4);
    const int r0c  = sub * 16;

    if (tid < 16) {
        const int row = r0c + tid;
        float m[NSPLIT];
        float M = -INFINITY;
        for (int q = 0; q < nact; ++q) {
            m[q] = mpart[(pb0 + q) * 256 + row];
            M = fmaxf(M, m[q]);
        }
        float L = 0.f;
        for (int q = 0; q < nact; ++q) {
            const float w = exp2f(m[q] - M);         // M finite (s<=cmax nonempty)
            ws[tid][q] = w;
            L += w * lpart[(pb0 + q) * 256 + row];
        }
        scl[tid] = 8.0f / L;                         // post-softmax * sqrt(64)
    }
    __syncthreads();

    const int rowl = tid >> 4;                       // 0..15
    const int c4   = tid & 15;                       // 4-col group
    const int row  = r0c + rowl;
    float a0 = 0.f, a1 = 0.f, a2 = 0.f, a3 = 0.f;
    for (int q = 0; q < nact; ++q) {
        const f16x4 v = *(const f16x4*)&Opart[(pb0 + q) * (256 * 64) + row * 64 + c4 * 4];
        const float w = ws[rowl][q];
        a0 += w * (float)v[0]; a1 += w * (float)v[1];
        a2 += w * (float)v[2]; a3 += w * (float)v[3];
    }
    const float s = scl[rowl];
    const float4 o = {a0 * s, a1 * s, a2 * s, a3 * s};
    *(float4*)&O[((size_t)bb * T + p * 256 + row) * DH + c4 * 4] = o;
}

extern "C" void kernel_launch(void* const* d_in, const int* in_sizes, int n_in,
                              void* d_out, int out_size, void* d_ws, size_t ws_size,
                              hipStream_t stream) {
    const float* x  = (const float*)d_in[0];
    const float* Wq = (const float*)d_in[1];
    const float* bq = (const float*)d_in[2];
    const float* Wk = (const float*)d_in[3];
    const float* bk = (const float*)d_in[4];
    const float* Wv = (const float*)d_in[5];
    const float* bv = (const float*)d_in[6];

    const size_t N  = (size_t)B * T * DH;       // 1,048,576
    f16* Qf = (f16*)d_ws;
    f16* Kf = Qf + N;
    f16* Vt = Kf + N;                           // [B, 64, T]
    f16* Wf = Vt + N;                           // [192, 512]
    f16* Opart = Wf + (size_t)192 * DEMB;       // 1024 x 256 x 64 fp16
    float* mpart = (float*)(Opart + (size_t)1024 * 256 * 64);
    float* lpart = mpart + (size_t)1024 * 256;

    convert_w<<<dim3(192 * DEMB / 256), dim3(256), 0, stream>>>(Wq, Wk, Wv, Wf);
    proj_mfma<<<dim3(B * T / 32), dim3(512), 0, stream>>>(
        x, Wf, bq, bk, bv, Qf, Kf, Vt);
    attn_partial<<<dim3(B * NPTILE * NSPLIT), dim3(512), 0, stream>>>(
        Qf, Kf, Vt, Opart, mpart, lpart);
    attn_combine<<<dim3(B * NPTILE * 16), dim3(256), 0, stream>>>(
        Opart, mpart, lpart, (float*)d_out);
}

// Round 11
// 132.628 us; speedup vs baseline: 1.0155x; 1.0155x over previous
//
#include <hip/hip_runtime.h>
#include <hip/hip_fp16.h>
#include <math.h>

#define B 4
#define T 4096
#define DEMB 512
#define DH 64
#define NSPLIT 8
#define NPTILE 16            // 256-row q-tiles per batch
#define LOG2E 1.44269504088896340736f

typedef _Float16 f16;
typedef __attribute__((ext_vector_type(4))) _Float16 f16x4;
typedef __attribute__((ext_vector_type(8))) _Float16 f16x8;
typedef __attribute__((ext_vector_type(4))) float f32x4;

__device__ __forceinline__ float fexp2(float x) {
    return __builtin_amdgcn_exp2f(x);          // bare v_exp_f32
}

// ---------------------------------------------------------------------------
// W prepass: concat Wq|Wk|Wv -> [192][512] fp16.
// ---------------------------------------------------------------------------
__global__ __launch_bounds__(256) void convert_w(
    const float* __restrict__ Wq, const float* __restrict__ Wk,
    const float* __restrict__ Wv, f16* __restrict__ Wf)
{
    const int idx = blockIdx.x * 256 + threadIdx.x;     // covers 192*512
    const int row = idx >> 9;
    const int k   = idx & 511;
    const float* W = row < 64 ? Wq : (row < 128 ? Wk : Wv);
    Wf[idx] = (f16)W[(row & 63) * DEMB + k];
}

// ---------------------------------------------------------------------------
// QKV projection, fp16 MFMA GEMM: [16384x512] x [512x192].
// 512 blocks x 8 waves; block = 32 x-rows; k-chunks of 128.
// Register PREFETCH: next chunk's x/W global loads issue right after the
// post-stage barrier, hiding global latency behind the MFMA compute.
// Wave = (rg = wv>>2: 16-row group) x (nh = wv&3: 3 of 12 n-tiles).
// Q written PRE-SCALED by log2(e) so attention softmax uses exp2.
// ---------------------------------------------------------------------------
__global__ __launch_bounds__(512) void proj_mfma(
    const float* __restrict__ x, const f16* __restrict__ Wfg,
    const float* __restrict__ bq, const float* __restrict__ bk,
    const float* __restrict__ bv,
    f16* __restrict__ Qf, f16* __restrict__ Kf, f16* __restrict__ Vt)
{
    __shared__ f16 xs[32][136];           // 8704 B (272 B rows)
    __shared__ f16 Ws[192][136];          // 52224 B -> 60928 B total

    const int tid  = threadIdx.x;
    const int wv   = tid >> 6;
    const int lane = tid & 63;
    const int i16  = lane & 15;
    const int quad = lane >> 4;
    const int rg   = wv >> 2;             // 16-row group 0..1
    const int nh   = wv & 3;              // n-quarter (3 tiles)
    const size_t r0 = (size_t)blockIdx.x * 32;

    const int xrow = tid >> 4, xg = tid & 15;            // x staging coords
    float4 xa, xb;                                       // x prefetch regs
    f16x8 wpre[6];                                       // W prefetch regs

    // preload chunk 0
    {
        xa = *(const float4*)(x + (r0 + xrow) * DEMB + xg * 8);
        xb = *(const float4*)(x + (r0 + xrow) * DEMB + xg * 8 + 4);
#pragma unroll
        for (int u = 0; u < 6; ++u) {
            const int idx = tid + 512 * u;
            const int row = idx >> 4, g = idx & 15;
            wpre[u] = *(const f16x8*)(Wfg + (size_t)row * DEMB + g * 8);
        }
    }

    f32x4 acc[3];
    const f32x4 zero = {0.f, 0.f, 0.f, 0.f};
#pragma unroll
    for (int n = 0; n < 3; ++n) acc[n] = zero;

    for (int cc = 0; cc < DEMB; cc += 128) {
        __syncthreads();                  // prior chunk's LDS reads done
        {
            f16x8 h = {(f16)xa.x, (f16)xa.y, (f16)xa.z, (f16)xa.w,
                       (f16)xb.x, (f16)xb.y, (f16)xb.z, (f16)xb.w};
            *(f16x8*)&xs[xrow][xg * 8] = h;
        }
#pragma unroll
        for (int u = 0; u < 6; ++u) {
            const int idx = tid + 512 * u;
            const int row = idx >> 4, g = idx & 15;
            *(f16x8*)&Ws[row][g * 8] = wpre[u];
        }
        __syncthreads();

        // prefetch next chunk (overlaps with MFMA below)
        if (cc + 128 < DEMB) {
            const int cn = cc + 128;
            xa = *(const float4*)(x + (r0 + xrow) * DEMB + cn + xg * 8);
            xb = *(const float4*)(x + (r0 + xrow) * DEMB + cn + xg * 8 + 4);
#pragma unroll
            for (int u = 0; u < 6; ++u) {
                const int idx = tid + 512 * u;
                const int row = idx >> 4, g = idx & 15;
                wpre[u] = *(const f16x8*)(Wfg + (size_t)row * DEMB + cn + g * 8);
            }
        }

#pragma unroll
        for (int kk = 0; kk < 4; ++kk) {
            const f16x8 af = *(const f16x8*)&xs[rg * 16 + i16][kk * 32 + quad * 8];
#pragma unroll
            for (int n = 0; n < 3; ++n) {
                const f16x8 bf = *(const f16x8*)&Ws[(nh * 3 + n) * 16 + i16][kk * 32 + quad * 8];
                acc[n] = __builtin_amdgcn_mfma_f32_16x16x32_f16(af, bf, acc[n], 0, 0, 0);
            }
        }
    }

    const size_t bb = r0 / T;                  // uniform per block (32 | 4096)
    const size_t t0 = r0 - bb * T;
#pragma unroll
    for (int n = 0; n < 3; ++n) {
        const int col = (nh * 3 + n) * 16 + i16;    // 0..191
        const int m = col >> 6, h = col & 63;
        const float bias = (m == 0 ? bq : (m == 1 ? bk : bv))[h];
#pragma unroll
        for (int r = 0; r < 4; ++r) {
            const int row = rg * 16 + quad * 4 + r;
            const float v = acc[n][r] + bias;
            const size_t grow = r0 + row;
            if (m == 0)      Qf[grow * DH + h] = (f16)(v * LOG2E);  // log2-domain
            else if (m == 1) Kf[grow * DH + h] = (f16)v;
            else             Vt[(bb * DH + h) * T + t0 + row] = (f16)v;
        }
    }
}

// ---------------------------------------------------------------------------
// Attention pass 1 (transposed layout, base-2 softmax, DOUBLE-BUFFERED K/V
// staging -> ONE barrier per chunk, register prefetch of next chunk).
// Barrier argument: write to buf^1 races nothing (readers are on buf); the
// single barrier before compute of iter i+1 orders everyone past iter i's
// reads before iter i+2 rewrites buf.
// Grid (b, ptile, split) = 4 x 16 x 8 = 512 blocks; block = 8 waves,
// each wave owns q-groups wv and wv+8 (2 x 16 rows) sharing K/V fragments.
// ---------------------------------------------------------------------------
__global__ __launch_bounds__(512) void attn_partial(
    const f16* __restrict__ Qf, const f16* __restrict__ Kf,
    const f16* __restrict__ Vt,
    f16* __restrict__ Opart, float* __restrict__ mpart,
    float* __restrict__ lpart)
{
    __shared__ f16 Ks[2][64][72], Vs[2][64][72];    // 36864 B
    __shared__ f16 Pl[8][16][72];                   // 18432 B -> 54 KB total

    const int tid  = threadIdx.x;
    const int wv   = tid >> 6;      // 0..7
    const int lane = tid & 63;
    const int i16  = lane & 15;
    const int quad = lane >> 4;

    const int s    = blockIdx.x & 7;
    const int p    = 15 - ((blockIdx.x >> 3) & 15);   // biggest tiles first
    const int bb   = blockIdx.x >> 7;
    const size_t base = (size_t)bb * T;
    const int row0 = p * 256;
    const int cmax = 4 * p + 3;
    if (s > cmax) return;                // p=0, s>=4: nothing (combine skips)
    const int rowg0 = row0 + wv * 16;
    const int rowg1 = row0 + (wv + 8) * 16;

    // Q B-frags (held in registers for the whole kernel)
    f16x8 qf00, qf01, qf10, qf11;
    {
        const f16* q0 = Qf + (base + rowg0 + i16) * DH;
        const f16* q1 = Qf + (base + rowg1 + i16) * DH;
        qf00 = *(const f16x8*)(q0 + quad * 8);
        qf01 = *(const f16x8*)(q0 + 32 + quad * 8);
        qf10 = *(const f16x8*)(q1 + quad * 8);
        qf11 = *(const f16x8*)(q1 + 32 + quad * 8);
    }

    f32x4 oacc[2][4];
    float mm[2] = {-INFINITY, -INFINITY}, ll[2] = {0.f, 0.f};
    const f32x4 zero = {0.f, 0.f, 0.f, 0.f};
#pragma unroll
    for (int j = 0; j < 2; ++j)
#pragma unroll
        for (int n = 0; n < 4; ++n) oacc[j][n] = zero;

    const int srow = tid >> 3, sg = tid & 7;
    f16x8 kpre, vpre;
    {
        const int kb = s << 6;
        kpre = *(const f16x8*)(Kf + (base + kb + srow) * DH + sg * 8);
        vpre = *(const f16x8*)(Vt + ((size_t)bb * DH + srow) * T + kb + sg * 8);
    }

    int buf = 0;
    for (int c = s; c <= cmax; c += NSPLIT) {
        // regs hold chunk c's K/V; write into current buffer
        *(f16x8*)&Ks[buf][srow][sg * 8] = kpre;
        *(f16x8*)&Vs[buf][srow][sg * 8] = vpre;
        __syncthreads();                 // single barrier per chunk

        const int cn = c + NSPLIT;       // prefetch next chunk (hidden by compute)
        if (cn <= cmax) {
            const int kbn = cn << 6;
            kpre = *(const f16x8*)(Kf + (base + kbn + srow) * DH + sg * 8);
            vpre = *(const f16x8*)(Vt + ((size_t)bb * DH + srow) * T + kbn + sg * 8);
        }

        const int kb = c << 6;
        const bool a0 = kb <= rowg0, a1 = kb <= rowg1;  // a0 => a1
        if (a1) {
            // ---- St = K·Q^T, shared K A-frags (scores in log2 units)
            f32x4 st[2][4];
#pragma unroll
            for (int kt = 0; kt < 4; ++kt) {
                const f16x8 kf0 = *(const f16x8*)&Ks[buf][kt * 16 + i16][quad * 8];
                const f16x8 kf1 = *(const f16x8*)&Ks[buf][kt * 16 + i16][32 + quad * 8];
                if (a0) {
                    f32x4 a = __builtin_amdgcn_mfma_f32_16x16x32_f16(kf0, qf00, zero, 0, 0, 0);
                    st[0][kt] = __builtin_amdgcn_mfma_f32_16x16x32_f16(kf1, qf01, a, 0, 0, 0);
                }
                {
                    f32x4 a = __builtin_amdgcn_mfma_f32_16x16x32_f16(kf0, qf10, zero, 0, 0, 0);
                    st[1][kt] = __builtin_amdgcn_mfma_f32_16x16x32_f16(kf1, qf11, a, 0, 0, 0);
                }
            }
            // ---- per-group softmax + P^T write + read-back
            f16x8 pf[2][2];
#pragma unroll
            for (int j = 0; j < 2; ++j) {
                if (j == 0 && !a0) continue;
                const int rowg = j == 0 ? rowg0 : rowg1;
                if (kb + 63 > rowg) {       // diagonal chunk: causal mask
#pragma unroll
                    for (int kt = 0; kt < 4; ++kt)
#pragma unroll
                        for (int r = 0; r < 4; ++r)
                            if (kb + kt * 16 + quad * 4 + r > rowg + i16)
                                st[j][kt][r] = -INFINITY;
                }
                float mx = -INFINITY;
#pragma unroll
                for (int kt = 0; kt < 4; ++kt)
#pragma unroll
                    for (int r = 0; r < 4; ++r) mx = fmaxf(mx, st[j][kt][r]);
                mx = fmaxf(mx, __shfl_xor(mx, 16, 64));
                mx = fmaxf(mx, __shfl_xor(mx, 32, 64));
                const float mnew = fmaxf(mm[j], mx);    // finite: kb <= rowg
                const float alpha = fexp2(mm[j] - mnew);
                mm[j] = mnew;
                float sum = 0.f;
#pragma unroll
                for (int kt = 0; kt < 4; ++kt) {
                    f16x4 pk;
#pragma unroll
                    for (int r = 0; r < 4; ++r) {
                        const f16 pb = (f16)fexp2(st[j][kt][r] - mnew);
                        pk[r] = pb;
                        sum += (float)pb;   // l sums ROUNDED p (matches PV)
                    }
                    *(f16x4*)&Pl[wv][i16][kt * 16 + quad * 4] = pk;
                }
                sum += __shfl_xor(sum, 16, 64);
                sum += __shfl_xor(sum, 32, 64);
                ll[j] = ll[j] * alpha + sum;
#pragma unroll
                for (int n = 0; n < 4; ++n) oacc[j][n] *= alpha;  // col=q: no shuffle
                pf[j][0] = *(const f16x8*)&Pl[wv][i16][quad * 8];
                pf[j][1] = *(const f16x8*)&Pl[wv][i16][32 + quad * 8];
            }
            // ---- O^T += V^T·P^T, shared V A-frags
#pragma unroll
            for (int mt = 0; mt < 4; ++mt) {
                const f16x8 vf0 = *(const f16x8*)&Vs[buf][mt * 16 + i16][quad * 8];
                const f16x8 vf1 = *(const f16x8*)&Vs[buf][mt * 16 + i16][32 + quad * 8];
                if (a0) {
                    oacc[0][mt] = __builtin_amdgcn_mfma_f32_16x16x32_f16(vf0, pf[0][0], oacc[0][mt], 0, 0, 0);
                    oacc[0][mt] = __builtin_amdgcn_mfma_f32_16x16x32_f16(vf1, pf[0][1], oacc[0][mt], 0, 0, 0);
                }
                oacc[1][mt] = __builtin_amdgcn_mfma_f32_16x16x32_f16(vf0, pf[1][0], oacc[1][mt], 0, 0, 0);
                oacc[1][mt] = __builtin_amdgcn_mfma_f32_16x16x32_f16(vf1, pf[1][1], oacc[1][mt], 0, 0, 0);
            }
        }
        buf ^= 1;
    }

    // ---- epilogue: O^T regs -> Opart rows (lane i16 = q)
    f16* Ob = Opart + (size_t)blockIdx.x * (256 * 64);
#pragma unroll
    for (int j = 0; j < 2; ++j) {
        const int prow = (wv + 8 * j) * 16 + i16;       // tile-local q-row
#pragma unroll
        for (int mt = 0; mt < 4; ++mt) {
            f16x4 pk = {(f16)oacc[j][mt][0], (f16)oacc[j][mt][1],
                        (f16)oacc[j][mt][2], (f16)oacc[j][mt][3]};
            *(f16x4*)&Ob[prow * 64 + mt * 16 + quad * 4] = pk;
        }
        if (quad == 0) {
            mpart[(size_t)blockIdx.x * 256 + prow] = mm[j];
            lpart[(size_t)blockIdx.x * 256 + prow] = ll[j];
        }
    }
}

// ---------------------------------------------------------------------------
// Attention pass 2: combine split-partials (base-2 weights).
// Grid (b, p, sub) = 4 x 16 x 16 = 1024 blocks; block = 16 rows.
// nact = min(8, 4p+4): splits beyond the causal frontier are skipped.
// ---------------------------------------------------------------------------
__global__ __launch_bounds__(256) void attn_combine(
    const f16* __restrict__ Opart, const float* __restrict__ mpart,
    const float* __restrict__ lpart, float* __restrict__ O)
{
    __shared__ float ws[16][NSPLIT];
    __shared__ float scl[16];

    const int tid = threadIdx.x;
    const int sub = blockIdx.x & 15;                 // 16-row slice
    const int p   = (blockIdx.x >> 4) & 15;
    const int bb  = blockIdx.x >> 8;
    const size_t pb0 = (size_t)bb * 128 + (15 - p) * NSPLIT;  // split block ids
    const int nact = min(NSPLIT, 4 * p + 4);
    const int r0c  = sub * 16;

    if (tid < 16) {
        const int row = r0c + tid;
        float m[NSPLIT];
        float M = -INFINITY;
        for (int q = 0; q < nact; ++q) {
            m[q] = mpart[(pb0 + q) * 256 + row];
            M = fmaxf(M, m[q]);
        }
        float L = 0.f;
        for (int q = 0; q < nact; ++q) {
            const float w = fexp2(m[q] - M);         // M finite (s<=cmax nonempty)
            ws[tid][q] = w;
            L += w * lpart[(pb0 + q) * 256 + row];
        }
        scl[tid] = 8.0f / L;                         // post-softmax * sqrt(64)
    }
    __syncthreads();

    const int rowl = tid >> 4;                       // 0..15
    const int c4   = tid & 15;                       // 4-col group
    const int row  = r0c + rowl;
    float a0 = 0.f, a1 = 0.f, a2 = 0.f, a3 = 0.f;
    for (int q = 0; q < nact; ++q) {
        const f16x4 v = *(const f16x4*)&Opart[(pb0 + q) * (256 * 64) + row * 64 + c4 * 4];
        const float w = ws[rowl][q];
        a0 += w * (float)v[0]; a1 += w * (float)v[1];
        a2 += w * (float)v[2]; a3 += w * (float)v[3];
    }
    const float s = scl[rowl];
    const float4 o = {a0 * s, a1 * s, a2 * s, a3 * s};
    *(float4*)&O[((size_t)bb * T + p * 256 + row) * DH + c4 * 4] = o;
}

extern "C" void kernel_launch(void* const* d_in, const int* in_sizes, int n_in,
                              void* d_out, int out_size, void* d_ws, size_t ws_size,
                              hipStream_t stream) {
    const float* x  = (const float*)d_in[0];
    const float* Wq = (const float*)d_in[1];
    const float* bq = (const float*)d_in[2];
    const float* Wk = (const float*)d_in[3];
    const float* bk = (const float*)d_in[4];
    const float* Wv = (const float*)d_in[5];
    const float* bv = (const float*)d_in[6];

    const size_t N  = (size_t)B * T * DH;       // 1,048,576
    f16* Qf = (f16*)d_ws;
    f16* Kf = Qf + N;
    f16* Vt = Kf + N;                           // [B, 64, T]
    f16* Wf = Vt + N;                           // [192, 512]
    f16* Opart = Wf + (size_t)192 * DEMB;       // 512 x 256 x 64 fp16
    float* mpart = (float*)(Opart + (size_t)512 * 256 * 64);
    float* lpart = mpart + (size_t)512 * 256;

    convert_w<<<dim3(192 * DEMB / 256), dim3(256), 0, stream>>>(Wq, Wk, Wv, Wf);
    proj_mfma<<<dim3(B * T / 32), dim3(512), 0, stream>>>(
        x, Wf, bq, bk, bv, Qf, Kf, Vt);
    attn_partial<<<dim3(B * NPTILE * NSPLIT), dim3(512), 0, stream>>>(
        Qf, Kf, Vt, Opart, mpart, lpart);
    attn_combine<<<dim3(B * NPTILE * 16), dim3(256), 0, stream>>>(
        Opart, mpart, lpart, (float*)d_out);
}